// Round 7
// baseline (784.093 us; speedup 1.0000x reference)
//
#include <hip/hip_runtime.h>

#define N_NODES 100000
#define N_EDGES 1600000
#define D_FEAT  64
#define NFEAT_ELEM (N_NODES * D_FEAT)                    // 6,400,000

#define BUCK_SHIFT 7
#define BUCK_NODES 128                                   // nodes per bucket
#define NBUCK ((N_NODES + BUCK_NODES - 1) / BUCK_NODES)  // 782
#define CUR_PAD 16

#define BIN_BLK 256
#define BIN_EPT 16
#define BIN_CHUNK (BIN_BLK * BIN_EPT)                    // 4096 edges/block
#define NCHUNK ((N_EDGES + BIN_CHUNK - 1) / BIN_CHUNK)   // 391

#define GATH_BLK 512                                     // 8 waves/bucket-block

typedef float          vf4 __attribute__((ext_vector_type(4)));
typedef int            vi4 __attribute__((ext_vector_type(4)));
typedef unsigned short vu4 __attribute__((ext_vector_type(4)));
typedef unsigned short ushort_t;

// ---------------------------------------------------------------------------
// Workspace layout:
//   bcnt  : int[NBUCK]
//   bbase : int[NBUCK+1]
//   bcur  : int[NBUCK*CUR_PAD]
//   ep    : int2[N_EDGES]        (.x = local_dst<<24 | src, .y = w bits)
//   featb : ushort[NFEAT_ELEM]   bf16 feature copy (12.8 MB, appended last)
// ---------------------------------------------------------------------------
#define OFF_BCNT  0
#define OFF_BBASE (OFF_BCNT + NBUCK * 4)
#define OFF_BCUR  (OFF_BBASE + (NBUCK + 1) * 4)
#define OFF_EP    (((OFF_BCUR + NBUCK * CUR_PAD * 4) + 255) & ~255)
#define OFF_FEATB (OFF_EP + N_EDGES * 8)
#define WS_MED    (size_t)OFF_FEATB
#define WS_FULL   (size_t)(OFF_FEATB + (size_t)NFEAT_ELEM * 2)

// fp32 -> bf16 (RNE) conversion of feat.
__global__ void k_prep(const float* __restrict__ feat, ushort_t* __restrict__ featb) {
    int i = blockIdx.x * blockDim.x + threadIdx.x;       // float4 index
    if (i < NFEAT_ELEM / 4) {
        vf4 x = ((const vf4*)feat)[i];
        vu4 r;
#pragma unroll
        for (int k = 0; k < 4; ++k) {
            unsigned b = __float_as_uint(x[k]);
            r[k] = (ushort_t)((b + 0x7fffu + ((b >> 16) & 1u)) >> 16);
        }
        __builtin_nontemporal_store(r, (vu4*)featb + i);
    }
}

__global__ void k_bhist(const int* __restrict__ dst, int* __restrict__ bcnt) {
    __shared__ int h[NBUCK];
    for (int i = threadIdx.x; i < NBUCK; i += blockDim.x) h[i] = 0;
    __syncthreads();
    const int n4 = N_EDGES / 4;                          // 400,000 exact
    const int stride = gridDim.x * blockDim.x;
    const vi4* d4 = (const vi4*)dst;
    for (int i = blockIdx.x * blockDim.x + threadIdx.x; i < n4; i += stride) {
        vi4 v = __builtin_nontemporal_load(d4 + i);
        atomicAdd(&h[v.x >> BUCK_SHIFT], 1);
        atomicAdd(&h[v.y >> BUCK_SHIFT], 1);
        atomicAdd(&h[v.z >> BUCK_SHIFT], 1);
        atomicAdd(&h[v.w >> BUCK_SHIFT], 1);
    }
    __syncthreads();
    for (int i = threadIdx.x; i < NBUCK; i += blockDim.x)
        if (h[i]) atomicAdd(&bcnt[i], h[i]);
}

// Exclusive scan of NBUCK (=782) counts in one 1024-thread block.
__global__ void k_bscan(const int* __restrict__ bcnt, int* __restrict__ bbase,
                        int* __restrict__ bcur) {
    __shared__ int tmp[1024];
    const int t = threadIdx.x;
    int v = (t < NBUCK) ? bcnt[t] : 0;
    tmp[t] = v;
    __syncthreads();
    for (int off = 1; off < 1024; off <<= 1) {
        int x = (t >= off) ? tmp[t - off] : 0;
        __syncthreads();
        tmp[t] += x;
        __syncthreads();
    }
    if (t < NBUCK) {
        int ex = tmp[t] - v;
        bbase[t] = ex;
        bcur[t * CUR_PAD] = ex;
    }
    if (t == 0) bbase[NBUCK] = N_EDGES;
}

// Chunked write-combining binning pass (unchanged from round 6; ~40 us).
__global__ __launch_bounds__(BIN_BLK) void k_bin(const int* __restrict__ src,
                                                 const int* __restrict__ dst,
                                                 const float* __restrict__ weight,
                                                 int* __restrict__ bcur,
                                                 int2* __restrict__ ep) {
    __shared__ int lcnt[NBUCK];
    __shared__ int lbase[NBUCK];
    const int t = threadIdx.x;
    const int e0 = blockIdx.x * BIN_CHUNK;
    for (int i = t; i < NBUCK; i += BIN_BLK) lcnt[i] = 0;
    __syncthreads();
    int bk[BIN_EPT], rk[BIN_EPT], xk[BIN_EPT], wk[BIN_EPT];
#pragma unroll
    for (int k = 0; k < BIN_EPT; ++k) {
        const int e = e0 + t + k * BIN_BLK;              // coalesced
        bk[k] = -1;
        if (e < N_EDGES) {
            int v = __builtin_nontemporal_load(dst + e);
            int s = __builtin_nontemporal_load(src + e);
            wk[k] = __builtin_nontemporal_load((const int*)weight + e);
            int b = v >> BUCK_SHIFT;
            bk[k] = b;
            xk[k] = ((v & (BUCK_NODES - 1)) << 24) | s;  // src < 2^17
            rk[k] = atomicAdd(&lcnt[b], 1);
        }
    }
    __syncthreads();
    for (int i = t; i < NBUCK; i += BIN_BLK) {
        int c = lcnt[i];
        if (c) lbase[i] = atomicAdd(&bcur[i * CUR_PAD], c);
    }
    __syncthreads();
#pragma unroll
    for (int k = 0; k < BIN_EPT; ++k)
        if (bk[k] >= 0) ep[lbase[bk[k]] + rk[k]] = make_int2(xk[k], wk[k]);
}

// One 512-thread block (8 waves) per 128-node bucket; 32 KB LDS accumulator.
// 4 blocks/CU (wave cap) -> ~32 waves/CU resident. bf16 feat rows = 128 B.
template <int BF16>
__global__ __launch_bounds__(GATH_BLK) void k_bgather(const float* __restrict__ feat,
                                                      const ushort_t* __restrict__ featb,
                                                      const float* __restrict__ bias,
                                                      const int* __restrict__ bbase,
                                                      const int2* __restrict__ ep,
                                                      float* __restrict__ out) {
    __shared__ float acc[BUCK_NODES * D_FEAT];           // 32 KB
    const int t = threadIdx.x;
    const int lane = t & 63;
    const int wid = t >> 6;                              // 0..7
    const int b = blockIdx.x;

    vf4* a4 = (vf4*)acc;
    for (int i = t; i < BUCK_NODES * D_FEAT / 4; i += GATH_BLK)
        a4[i] = (vf4){0.f, 0.f, 0.f, 0.f};
    __syncthreads();

    const int g0 = bbase[b];
    const int g1 = bbase[b + 1];
    const long long* epq = (const long long*)ep;

#define FLOAD(X) (BF16 ? __uint_as_float(((unsigned)featb[((X) & 0xFFFFFF) * D_FEAT + lane]) << 16) \
                       : feat[((X) & 0xFFFFFF) * D_FEAT + lane])
#define ACC_ADD(X, V)                                                          \
    __hip_atomic_fetch_add(&acc[((unsigned)(X) >> 24) * D_FEAT + lane], (V),   \
                           __ATOMIC_RELAXED, __HIP_MEMORY_SCOPE_WORKGROUP)

    for (int base = g0 + wid * 64; base < g1; base += GATH_BLK) {
        const int n = min(64, g1 - base);
        long long q = 0;
        if (base + lane < g1) q = __builtin_nontemporal_load(epq + base + lane);
        const int px = (int)(q & 0xffffffffLL);
        const int pw = (int)(q >> 32);
        int j = 0;
        for (; j + 8 <= n; j += 8) {
            int x0 = __shfl(px, j + 0); float w0 = __int_as_float(__shfl(pw, j + 0));
            int x1 = __shfl(px, j + 1); float w1 = __int_as_float(__shfl(pw, j + 1));
            int x2 = __shfl(px, j + 2); float w2 = __int_as_float(__shfl(pw, j + 2));
            int x3 = __shfl(px, j + 3); float w3 = __int_as_float(__shfl(pw, j + 3));
            int x4 = __shfl(px, j + 4); float w4 = __int_as_float(__shfl(pw, j + 4));
            int x5 = __shfl(px, j + 5); float w5 = __int_as_float(__shfl(pw, j + 5));
            int x6 = __shfl(px, j + 6); float w6 = __int_as_float(__shfl(pw, j + 6));
            int x7 = __shfl(px, j + 7); float w7 = __int_as_float(__shfl(pw, j + 7));
            float f0 = FLOAD(x0);
            float f1 = FLOAD(x1);
            float f2 = FLOAD(x2);
            float f3 = FLOAD(x3);
            float f4 = FLOAD(x4);
            float f5 = FLOAD(x5);
            float f6 = FLOAD(x6);
            float f7 = FLOAD(x7);
            ACC_ADD(x0, w0 * f0); ACC_ADD(x1, w1 * f1);
            ACC_ADD(x2, w2 * f2); ACC_ADD(x3, w3 * f3);
            ACC_ADD(x4, w4 * f4); ACC_ADD(x5, w5 * f5);
            ACC_ADD(x6, w6 * f6); ACC_ADD(x7, w7 * f7);
        }
        for (; j < n; ++j) {
            int   x = __shfl(px, j);
            float w = __int_as_float(__shfl(pw, j));
            ACC_ADD(x, w * FLOAD(x));
        }
    }
#undef ACC_ADD
#undef FLOAD
    __syncthreads();

    // bias-fused float4 epilogue; stride 512 mod 16 == 0 -> (t&15) constant.
    const vf4 b4 = ((const vf4*)bias)[t & 15];
    const int vbase = b * BUCK_NODES;
    for (int f = t; f < BUCK_NODES * (D_FEAT / 4); f += GATH_BLK) {
        int row = f >> 4;
        if (vbase + row < N_NODES) {
            vf4 a = a4[f] + b4;
            __builtin_nontemporal_store(a, (vf4*)&out[(size_t)(vbase + row) * D_FEAT] + (f & 15));
        }
    }
}

// ---------------- fallback (ws too small): direct atomic path ---------------
__global__ void init_out_kernel(const float* __restrict__ bias,
                                float* __restrict__ out) {
    int i = blockIdx.x * blockDim.x + threadIdx.x;
    if (i < N_NODES * D_FEAT) out[i] = bias[i & (D_FEAT - 1)];
}

__global__ void edge_scatter_kernel(const float* __restrict__ feat,
                                    const float* __restrict__ weight,
                                    const int* __restrict__ src,
                                    const int* __restrict__ dst,
                                    float* __restrict__ out) {
    int e = blockIdx.x * 4 + (threadIdx.x >> 6);
    int lane = threadIdx.x & 63;
    if (e < N_EDGES) {
        atomicAdd(&out[dst[e] * D_FEAT + lane], weight[e] * feat[src[e] * D_FEAT + lane]);
    }
}

extern "C" void kernel_launch(void* const* d_in, const int* in_sizes, int n_in,
                              void* d_out, int out_size, void* d_ws, size_t ws_size,
                              hipStream_t stream) {
    const float* feat   = (const float*)d_in[0];
    const float* weight = (const float*)d_in[1];
    const float* bias   = (const float*)d_in[2];
    const int*   src    = (const int*)d_in[3];
    const int*   dst    = (const int*)d_in[4];
    float* out = (float*)d_out;

    if (ws_size < WS_MED) {
        int total = N_NODES * D_FEAT;
        init_out_kernel<<<(total + 255) / 256, 256, 0, stream>>>(bias, out);
        edge_scatter_kernel<<<(N_EDGES + 3) / 4, 256, 0, stream>>>(feat, weight, src, dst, out);
        return;
    }

    char* ws = (char*)d_ws;
    int*      bcnt  = (int*)(ws + OFF_BCNT);
    int*      bbase = (int*)(ws + OFF_BBASE);
    int*      bcur  = (int*)(ws + OFF_BCUR);
    int2*     ep    = (int2*)(ws + OFF_EP);
    ushort_t* featb = (ushort_t*)(ws + OFF_FEATB);
    const bool use_bf16 = (ws_size >= WS_FULL);

    (void)hipMemsetAsync(bcnt, 0, NBUCK * sizeof(int), stream);
    if (use_bf16)
        k_prep<<<(NFEAT_ELEM / 4 + 255) / 256, 256, 0, stream>>>(feat, featb);
    k_bhist<<<256, 256, 0, stream>>>(dst, bcnt);
    k_bscan<<<1, 1024, 0, stream>>>(bcnt, bbase, bcur);
    k_bin<<<NCHUNK, BIN_BLK, 0, stream>>>(src, dst, weight, bcur, ep);
    if (use_bf16)
        k_bgather<1><<<NBUCK, GATH_BLK, 0, stream>>>(feat, featb, bias, bbase, ep, out);
    else
        k_bgather<0><<<NBUCK, GATH_BLK, 0, stream>>>(feat, featb, bias, bbase, ep, out);
}

// Round 8
// 781.474 us; speedup vs baseline: 1.0034x; 1.0034x over previous
//
#include <hip/hip_runtime.h>

#define N_NODES 100000
#define N_EDGES 1600000
#define D_FEAT  64
#define NFEAT_ELEM (N_NODES * D_FEAT)                    // 6,400,000

#define BUCK_SHIFT 7
#define BUCK_NODES 128                                   // nodes per bucket
#define NBUCK ((N_NODES + BUCK_NODES - 1) / BUCK_NODES)  // 782
#define CUR_PAD 16

#define BIN_BLK 256
#define BIN_EPT 16
#define BIN_CHUNK (BIN_BLK * BIN_EPT)                    // 4096 edges/block
#define NCHUNK ((N_EDGES + BIN_CHUNK - 1) / BIN_CHUNK)   // 391

#define GATH_BLK 512                                     // 8 waves/bucket-block

typedef float          vf4 __attribute__((ext_vector_type(4)));
typedef int            vi4 __attribute__((ext_vector_type(4)));
typedef unsigned short vu4 __attribute__((ext_vector_type(4)));
typedef unsigned short ushort_t;

// ---------------------------------------------------------------------------
// Workspace layout:
//   bcnt  : int[NBUCK]
//   bbase : int[NBUCK+1]
//   bcur  : int[NBUCK*CUR_PAD]
//   ep    : int2[N_EDGES]        (.x = local_dst<<24 | src, .y = w bits)
//   featb : ushort[NFEAT_ELEM]   bf16 feature copy (12.8 MB)
// ---------------------------------------------------------------------------
#define OFF_BCNT  0
#define OFF_BBASE (OFF_BCNT + NBUCK * 4)
#define OFF_BCUR  (OFF_BBASE + (NBUCK + 1) * 4)
#define OFF_EP    (((OFF_BCUR + NBUCK * CUR_PAD * 4) + 255) & ~255)
#define OFF_FEATB (OFF_EP + N_EDGES * 8)
#define WS_MED    (size_t)OFF_FEATB
#define WS_FULL   (size_t)(OFF_FEATB + (size_t)NFEAT_ELEM * 2)

// fp32 -> bf16 (RNE) conversion of feat.
__global__ void k_prep(const float* __restrict__ feat, ushort_t* __restrict__ featb) {
    int i = blockIdx.x * blockDim.x + threadIdx.x;       // float4 index
    if (i < NFEAT_ELEM / 4) {
        vf4 x = ((const vf4*)feat)[i];
        vu4 r;
#pragma unroll
        for (int k = 0; k < 4; ++k) {
            unsigned b = __float_as_uint(x[k]);
            r[k] = (ushort_t)((b + 0x7fffu + ((b >> 16) & 1u)) >> 16);
        }
        __builtin_nontemporal_store(r, (vu4*)featb + i);
    }
}

__global__ void k_bhist(const int* __restrict__ dst, int* __restrict__ bcnt) {
    __shared__ int h[NBUCK];
    for (int i = threadIdx.x; i < NBUCK; i += blockDim.x) h[i] = 0;
    __syncthreads();
    const int n4 = N_EDGES / 4;                          // 400,000 exact
    const int stride = gridDim.x * blockDim.x;
    const vi4* d4 = (const vi4*)dst;
    for (int i = blockIdx.x * blockDim.x + threadIdx.x; i < n4; i += stride) {
        vi4 v = __builtin_nontemporal_load(d4 + i);
        atomicAdd(&h[v.x >> BUCK_SHIFT], 1);
        atomicAdd(&h[v.y >> BUCK_SHIFT], 1);
        atomicAdd(&h[v.z >> BUCK_SHIFT], 1);
        atomicAdd(&h[v.w >> BUCK_SHIFT], 1);
    }
    __syncthreads();
    for (int i = threadIdx.x; i < NBUCK; i += blockDim.x)
        if (h[i]) atomicAdd(&bcnt[i], h[i]);
}

// Exclusive scan of NBUCK (=782) counts in one 1024-thread block.
__global__ void k_bscan(const int* __restrict__ bcnt, int* __restrict__ bbase,
                        int* __restrict__ bcur) {
    __shared__ int tmp[1024];
    const int t = threadIdx.x;
    int v = (t < NBUCK) ? bcnt[t] : 0;
    tmp[t] = v;
    __syncthreads();
    for (int off = 1; off < 1024; off <<= 1) {
        int x = (t >= off) ? tmp[t - off] : 0;
        __syncthreads();
        tmp[t] += x;
        __syncthreads();
    }
    if (t < NBUCK) {
        int ex = tmp[t] - v;
        bbase[t] = ex;
        bcur[t * CUR_PAD] = ex;
    }
    if (t == 0) bbase[NBUCK] = N_EDGES;
}

// Chunked write-combining binning pass (unchanged; ~45 us).
__global__ __launch_bounds__(BIN_BLK) void k_bin(const int* __restrict__ src,
                                                 const int* __restrict__ dst,
                                                 const float* __restrict__ weight,
                                                 int* __restrict__ bcur,
                                                 int2* __restrict__ ep) {
    __shared__ int lcnt[NBUCK];
    __shared__ int lbase[NBUCK];
    const int t = threadIdx.x;
    const int e0 = blockIdx.x * BIN_CHUNK;
    for (int i = t; i < NBUCK; i += BIN_BLK) lcnt[i] = 0;
    __syncthreads();
    int bk[BIN_EPT], rk[BIN_EPT], xk[BIN_EPT], wk[BIN_EPT];
#pragma unroll
    for (int k = 0; k < BIN_EPT; ++k) {
        const int e = e0 + t + k * BIN_BLK;              // coalesced
        bk[k] = -1;
        if (e < N_EDGES) {
            int v = __builtin_nontemporal_load(dst + e);
            int s = __builtin_nontemporal_load(src + e);
            wk[k] = __builtin_nontemporal_load((const int*)weight + e);
            int b = v >> BUCK_SHIFT;
            bk[k] = b;
            xk[k] = ((v & (BUCK_NODES - 1)) << 24) | s;  // src < 2^17
            rk[k] = atomicAdd(&lcnt[b], 1);
        }
    }
    __syncthreads();
    for (int i = t; i < NBUCK; i += BIN_BLK) {
        int c = lcnt[i];
        if (c) lbase[i] = atomicAdd(&bcur[i * CUR_PAD], c);
    }
    __syncthreads();
#pragma unroll
    for (int k = 0; k < BIN_EPT; ++k)
        if (bk[k] >= 0) ep[lbase[bk[k]] + rk[k]] = make_int2(xk[k], wk[k]);
}

// One 512-thread block (8 waves) per 128-node bucket; 32 KB LDS accumulator.
// __launch_bounds__(512, 6): min 6 waves/SIMD -> VGPR cap ~84, so the 8-deep
// unrolled row loads can STAY IN FLIGHT (round-7's 20-VGPR allocation forced
// MLP~1 -> full latency per edge; this is the fix).
template <int BF16>
__global__ __launch_bounds__(GATH_BLK, 6) void k_bgather(const float* __restrict__ feat,
                                                         const ushort_t* __restrict__ featb,
                                                         const float* __restrict__ bias,
                                                         const int* __restrict__ bbase,
                                                         const int2* __restrict__ ep,
                                                         float* __restrict__ out) {
    __shared__ float acc[BUCK_NODES * D_FEAT];           // 32 KB
    const int t = threadIdx.x;
    const int lane = t & 63;
    const int wid = t >> 6;                              // 0..7
    const int b = blockIdx.x;

    vf4* a4 = (vf4*)acc;
    for (int i = t; i < BUCK_NODES * D_FEAT / 4; i += GATH_BLK)
        a4[i] = (vf4){0.f, 0.f, 0.f, 0.f};
    __syncthreads();

    const int g0 = bbase[b];
    const int g1 = bbase[b + 1];
    const long long* epq = (const long long*)ep;

#define FLOAD(X) (BF16 ? __uint_as_float(((unsigned)featb[((X) & 0xFFFFFF) * D_FEAT + lane]) << 16) \
                       : feat[((X) & 0xFFFFFF) * D_FEAT + lane])
#define ACC_ADD(X, V)                                                          \
    __hip_atomic_fetch_add(&acc[((unsigned)(X) >> 24) * D_FEAT + lane], (V),   \
                           __ATOMIC_RELAXED, __HIP_MEMORY_SCOPE_WORKGROUP)
#define GROUP8(J)                                                              \
    {                                                                          \
        int x0 = __shfl(px, (J) + 0); float w0 = __int_as_float(__shfl(pw, (J) + 0)); \
        int x1 = __shfl(px, (J) + 1); float w1 = __int_as_float(__shfl(pw, (J) + 1)); \
        int x2 = __shfl(px, (J) + 2); float w2 = __int_as_float(__shfl(pw, (J) + 2)); \
        int x3 = __shfl(px, (J) + 3); float w3 = __int_as_float(__shfl(pw, (J) + 3)); \
        int x4 = __shfl(px, (J) + 4); float w4 = __int_as_float(__shfl(pw, (J) + 4)); \
        int x5 = __shfl(px, (J) + 5); float w5 = __int_as_float(__shfl(pw, (J) + 5)); \
        int x6 = __shfl(px, (J) + 6); float w6 = __int_as_float(__shfl(pw, (J) + 6)); \
        int x7 = __shfl(px, (J) + 7); float w7 = __int_as_float(__shfl(pw, (J) + 7)); \
        float f0 = FLOAD(x0);                                                  \
        float f1 = FLOAD(x1);                                                  \
        float f2 = FLOAD(x2);                                                  \
        float f3 = FLOAD(x3);                                                  \
        float f4 = FLOAD(x4);                                                  \
        float f5 = FLOAD(x5);                                                  \
        float f6 = FLOAD(x6);                                                  \
        float f7 = FLOAD(x7);                                                  \
        ACC_ADD(x0, w0 * f0); ACC_ADD(x1, w1 * f1);                            \
        ACC_ADD(x2, w2 * f2); ACC_ADD(x3, w3 * f3);                            \
        ACC_ADD(x4, w4 * f4); ACC_ADD(x5, w5 * f5);                            \
        ACC_ADD(x6, w6 * f6); ACC_ADD(x7, w7 * f7);                            \
    }

    for (int base = g0 + wid * 64; base < g1; base += GATH_BLK) {
        if (base + 64 <= g1) {
            // full chunk: compile-time trip counts, no tail predicates
            long long q = __builtin_nontemporal_load(epq + base + lane);
            const int px = (int)(q & 0xffffffffLL);
            const int pw = (int)(q >> 32);
#pragma unroll
            for (int j = 0; j < 64; j += 8) GROUP8(j)
        } else {
            const int n = g1 - base;
            long long q = 0;
            if (base + lane < g1) q = __builtin_nontemporal_load(epq + base + lane);
            const int px = (int)(q & 0xffffffffLL);
            const int pw = (int)(q >> 32);
            int j = 0;
            for (; j + 8 <= n; j += 8) GROUP8(j)
            for (; j < n; ++j) {
                int   x = __shfl(px, j);
                float w = __int_as_float(__shfl(pw, j));
                ACC_ADD(x, w * FLOAD(x));
            }
        }
    }
#undef GROUP8
#undef ACC_ADD
#undef FLOAD
    __syncthreads();

    // bias-fused float4 epilogue; stride 512 mod 16 == 0 -> (t&15) constant.
    const vf4 b4 = ((const vf4*)bias)[t & 15];
    const int vbase = b * BUCK_NODES;
    for (int f = t; f < BUCK_NODES * (D_FEAT / 4); f += GATH_BLK) {
        int row = f >> 4;
        if (vbase + row < N_NODES) {
            vf4 a = a4[f] + b4;
            __builtin_nontemporal_store(a, (vf4*)&out[(size_t)(vbase + row) * D_FEAT] + (f & 15));
        }
    }
}

// ---------------- fallback (ws too small): direct atomic path ---------------
__global__ void init_out_kernel(const float* __restrict__ bias,
                                float* __restrict__ out) {
    int i = blockIdx.x * blockDim.x + threadIdx.x;
    if (i < N_NODES * D_FEAT) out[i] = bias[i & (D_FEAT - 1)];
}

__global__ void edge_scatter_kernel(const float* __restrict__ feat,
                                    const float* __restrict__ weight,
                                    const int* __restrict__ src,
                                    const int* __restrict__ dst,
                                    float* __restrict__ out) {
    int e = blockIdx.x * 4 + (threadIdx.x >> 6);
    int lane = threadIdx.x & 63;
    if (e < N_EDGES) {
        atomicAdd(&out[dst[e] * D_FEAT + lane], weight[e] * feat[src[e] * D_FEAT + lane]);
    }
}

extern "C" void kernel_launch(void* const* d_in, const int* in_sizes, int n_in,
                              void* d_out, int out_size, void* d_ws, size_t ws_size,
                              hipStream_t stream) {
    const float* feat   = (const float*)d_in[0];
    const float* weight = (const float*)d_in[1];
    const float* bias   = (const float*)d_in[2];
    const int*   src    = (const int*)d_in[3];
    const int*   dst    = (const int*)d_in[4];
    float* out = (float*)d_out;

    if (ws_size < WS_MED) {
        int total = N_NODES * D_FEAT;
        init_out_kernel<<<(total + 255) / 256, 256, 0, stream>>>(bias, out);
        edge_scatter_kernel<<<(N_EDGES + 3) / 4, 256, 0, stream>>>(feat, weight, src, dst, out);
        return;
    }

    char* ws = (char*)d_ws;
    int*      bcnt  = (int*)(ws + OFF_BCNT);
    int*      bbase = (int*)(ws + OFF_BBASE);
    int*      bcur  = (int*)(ws + OFF_BCUR);
    int2*     ep    = (int2*)(ws + OFF_EP);
    ushort_t* featb = (ushort_t*)(ws + OFF_FEATB);
    const bool use_bf16 = (ws_size >= WS_FULL);

    (void)hipMemsetAsync(bcnt, 0, NBUCK * sizeof(int), stream);
    if (use_bf16)
        k_prep<<<(NFEAT_ELEM / 4 + 255) / 256, 256, 0, stream>>>(feat, featb);
    k_bhist<<<256, 256, 0, stream>>>(dst, bcnt);
    k_bscan<<<1, 1024, 0, stream>>>(bcnt, bbase, bcur);
    k_bin<<<NCHUNK, BIN_BLK, 0, stream>>>(src, dst, weight, bcur, ep);
    if (use_bf16)
        k_bgather<1><<<NBUCK, GATH_BLK, 0, stream>>>(feat, featb, bias, bbase, ep, out);
    else
        k_bgather<0><<<NBUCK, GATH_BLK, 0, stream>>>(feat, featb, bias, bbase, ep, out);
}

// Round 9
// 109.444 us; speedup vs baseline: 7.1643x; 7.1404x over previous
//
#include <hip/hip_runtime.h>

#define N_NODES 100000
#define N_EDGES 1600000
#define D_FEAT  64
#define NFEAT_ELEM (N_NODES * D_FEAT)                    // 6,400,000

#define BUCK_SHIFT 7
#define BUCK_NODES 128                                   // nodes per bucket
#define NBUCK ((N_NODES + BUCK_NODES - 1) / BUCK_NODES)  // 782
#define CUR_PAD 16

#define BIN_BLK 256
#define BIN_EPT 16
#define BIN_CHUNK (BIN_BLK * BIN_EPT)                    // 4096 edges/block
#define NCHUNK ((N_EDGES + BIN_CHUNK - 1) / BIN_CHUNK)   // 391

// gather: 2 blocks per bucket, each owns 64 nodes
#define GB_BLK   256                                     // 4 waves
#define GB_EPT   12                                      // 12*256=3072 >= max bucket (~2300)
#define GB_CAP   2048                                    // sorted-edge LDS capacity (kept ~1023)
#define HALF_NODES 64

typedef float          vf4 __attribute__((ext_vector_type(4)));
typedef float          vf2 __attribute__((ext_vector_type(2)));
typedef int            vi4 __attribute__((ext_vector_type(4)));
typedef unsigned short vu4 __attribute__((ext_vector_type(4)));
typedef unsigned short ushort_t;

// ---------------------------------------------------------------------------
// Workspace layout:
//   bcnt  : int[NBUCK]
//   bbase : int[NBUCK+1]
//   bcur  : int[NBUCK*CUR_PAD]
//   ep    : int2[N_EDGES]        (.x = local_dst<<24 | src, .y = w bits)
//   featb : ushort[NFEAT_ELEM]   bf16 feature copy (12.8 MB)
// ---------------------------------------------------------------------------
#define OFF_BCNT  0
#define OFF_BBASE (OFF_BCNT + NBUCK * 4)
#define OFF_BCUR  (OFF_BBASE + (NBUCK + 1) * 4)
#define OFF_EP    (((OFF_BCUR + NBUCK * CUR_PAD * 4) + 255) & ~255)
#define OFF_FEATB (OFF_EP + N_EDGES * 8)
#define WS_MED    (size_t)OFF_FEATB
#define WS_FULL   (size_t)(OFF_FEATB + (size_t)NFEAT_ELEM * 2)

// fp32 -> bf16 (RNE) conversion of feat.
__global__ void k_prep(const float* __restrict__ feat, ushort_t* __restrict__ featb) {
    int i = blockIdx.x * blockDim.x + threadIdx.x;       // float4 index
    if (i < NFEAT_ELEM / 4) {
        vf4 x = ((const vf4*)feat)[i];
        vu4 r;
#pragma unroll
        for (int k = 0; k < 4; ++k) {
            unsigned b = __float_as_uint(x[k]);
            r[k] = (ushort_t)((b + 0x7fffu + ((b >> 16) & 1u)) >> 16);
        }
        __builtin_nontemporal_store(r, (vu4*)featb + i);
    }
}

__global__ void k_bhist(const int* __restrict__ dst, int* __restrict__ bcnt) {
    __shared__ int h[NBUCK];
    for (int i = threadIdx.x; i < NBUCK; i += blockDim.x) h[i] = 0;
    __syncthreads();
    const int n4 = N_EDGES / 4;                          // 400,000 exact
    const int stride = gridDim.x * blockDim.x;
    const vi4* d4 = (const vi4*)dst;
    for (int i = blockIdx.x * blockDim.x + threadIdx.x; i < n4; i += stride) {
        vi4 v = __builtin_nontemporal_load(d4 + i);
        atomicAdd(&h[v.x >> BUCK_SHIFT], 1);
        atomicAdd(&h[v.y >> BUCK_SHIFT], 1);
        atomicAdd(&h[v.z >> BUCK_SHIFT], 1);
        atomicAdd(&h[v.w >> BUCK_SHIFT], 1);
    }
    __syncthreads();
    for (int i = threadIdx.x; i < NBUCK; i += blockDim.x)
        if (h[i]) atomicAdd(&bcnt[i], h[i]);
}

// Exclusive scan of NBUCK (=782) counts in one 1024-thread block.
__global__ void k_bscan(const int* __restrict__ bcnt, int* __restrict__ bbase,
                        int* __restrict__ bcur) {
    __shared__ int tmp[1024];
    const int t = threadIdx.x;
    int v = (t < NBUCK) ? bcnt[t] : 0;
    tmp[t] = v;
    __syncthreads();
    for (int off = 1; off < 1024; off <<= 1) {
        int x = (t >= off) ? tmp[t - off] : 0;
        __syncthreads();
        tmp[t] += x;
        __syncthreads();
    }
    if (t < NBUCK) {
        int ex = tmp[t] - v;
        bbase[t] = ex;
        bcur[t * CUR_PAD] = ex;
    }
    if (t == 0) bbase[NBUCK] = N_EDGES;
}

// Chunked write-combining binning pass (unchanged).
__global__ __launch_bounds__(BIN_BLK) void k_bin(const int* __restrict__ src,
                                                 const int* __restrict__ dst,
                                                 const float* __restrict__ weight,
                                                 int* __restrict__ bcur,
                                                 int2* __restrict__ ep) {
    __shared__ int lcnt[NBUCK];
    __shared__ int lbase[NBUCK];
    const int t = threadIdx.x;
    const int e0 = blockIdx.x * BIN_CHUNK;
    for (int i = t; i < NBUCK; i += BIN_BLK) lcnt[i] = 0;
    __syncthreads();
    int bk[BIN_EPT], rk[BIN_EPT], xk[BIN_EPT], wk[BIN_EPT];
#pragma unroll
    for (int k = 0; k < BIN_EPT; ++k) {
        const int e = e0 + t + k * BIN_BLK;              // coalesced
        bk[k] = -1;
        if (e < N_EDGES) {
            int v = __builtin_nontemporal_load(dst + e);
            int s = __builtin_nontemporal_load(src + e);
            wk[k] = __builtin_nontemporal_load((const int*)weight + e);
            int b = v >> BUCK_SHIFT;
            bk[k] = b;
            xk[k] = ((v & (BUCK_NODES - 1)) << 24) | s;  // src < 2^17
            rk[k] = atomicAdd(&lcnt[b], 1);
        }
    }
    __syncthreads();
    for (int i = t; i < NBUCK; i += BIN_BLK) {
        int c = lcnt[i];
        if (c) lbase[i] = atomicAdd(&bcur[i * CUR_PAD], c);
    }
    __syncthreads();
#pragma unroll
    for (int k = 0; k < BIN_EPT; ++k)
        if (bk[k] >= 0) ep[lbase[bk[k]] + rk[k]] = make_int2(xk[k], wk[k]);
}

// Sort-in-LDS + register-accumulator gather. 2 blocks per bucket; block owns
// 64 nodes. Phase 2: read bucket edges, keep own half, LDS rank. Phase 3:
// scan. Phase 4: scatter into sorted LDS lists. Phase 5: per-node register
// accumulation; half-wave pair trick (lane<32 even edges, lane>=32 odd; each
// lane loads a 4B packed pair of dims) -> one instr covers 2 rows; shfl_xor
// merges. One NT float2 store per node, bias fused. No output atomics.
template <int BF16>
__global__ __launch_bounds__(GB_BLK, 6) void k_sgather(const float* __restrict__ feat,
                                                       const ushort_t* __restrict__ featb,
                                                       const float* __restrict__ bias,
                                                       const int* __restrict__ bbase,
                                                       const int2* __restrict__ ep,
                                                       float* __restrict__ out) {
    __shared__ int   sx[GB_CAP];
    __shared__ float sw[GB_CAP];
    __shared__ int   cnt[HALF_NODES];
    __shared__ int   off[HALF_NODES];

    const int t = threadIdx.x;
    const int lane = t & 63;
    const int wid = t >> 6;                              // 0..3
    const int bk = blockIdx.x >> 1;                      // bucket
    const int rlo = (blockIdx.x & 1) * HALF_NODES;       // node-half base
    const int g0 = bbase[bk];
    const int g1 = bbase[bk + 1];
    const int nE = g1 - g0;
    const int nEc = nE > GB_EPT * GB_BLK ? GB_EPT * GB_BLK : nE;

    if (t < HALF_NODES) cnt[t] = 0;
    __syncthreads();

    // Phase 2: load + keep-filter + rank
    int   xk[GB_EPT];
    float wk[GB_EPT];
    int   rk[GB_EPT];
#pragma unroll
    for (int k = 0; k < GB_EPT; ++k) {
        const int idx = t + k * GB_BLK;
        xk[k] = -1;
        if (idx < nEc) {
            int2 e = ep[g0 + idx];
            int r = ((unsigned)e.x >> 24) - rlo;
            if ((unsigned)r < HALF_NODES) {
                xk[k] = e.x;
                wk[k] = __int_as_float(e.y);
                rk[k] = atomicAdd(&cnt[r], 1);
            }
        }
    }
    __syncthreads();

    // Phase 3: inclusive scan cnt -> off (64 entries)
    if (t < HALF_NODES) off[t] = cnt[t];
    __syncthreads();
    for (int d = 1; d < HALF_NODES; d <<= 1) {
        int v = 0;
        if (t < HALF_NODES && t >= d) v = off[t - d];
        __syncthreads();
        if (t < HALF_NODES) off[t] += v;
        __syncthreads();
    }

    // Phase 4: scatter into sorted lists
    int lmask = 0;
#pragma unroll
    for (int k = 0; k < GB_EPT; ++k) {
        if (xk[k] != -1) {
            int r = ((unsigned)xk[k] >> 24) - rlo;
            int pos = off[r] - cnt[r] + rk[k];
            if (pos < GB_CAP) {
                sx[pos] = xk[k] & 0xFFFFFF;
                sw[pos] = wk[k];
            } else {
                lmask |= 1 << k;                          // overflow (p~0)
            }
        }
    }
    __syncthreads();

    // Phase 5: per-node register accumulation
    const int col = lane & 31;
    const int half = lane >> 5;
    const vf2 b2 = ((const vf2*)bias)[col];
    for (int rr = 0; rr < 16; ++rr) {
        const int r = wid * 16 + rr;
        const int c = cnt[r];
        const int e0 = off[r] - c;
        float a0 = 0.f, a1 = 0.f;
        for (int i = 0; i < c; i += 8) {
#pragma unroll
            for (int k = 0; k < 4; ++k) {
                const int ei = i + 2 * k + half;
                const int   s = (ei < c) ? sx[e0 + ei] : 0;
                const float w = (ei < c) ? sw[e0 + ei] : 0.f;
                if (BF16) {
                    unsigned d = *((const unsigned*)(featb + s * D_FEAT) + col);
                    a0 = fmaf(w, __uint_as_float(d << 16), a0);
                    a1 = fmaf(w, __uint_as_float(d & 0xFFFF0000u), a1);
                } else {
                    vf2 fv = *((const vf2*)(feat + s * D_FEAT) + col);
                    a0 = fmaf(w, fv.x, a0);
                    a1 = fmaf(w, fv.y, a1);
                }
            }
        }
        a0 += __shfl_xor(a0, 32);
        a1 += __shfl_xor(a1, 32);
        const int node = bk * BUCK_NODES + rlo + r;
        if (half == 0 && node < N_NODES) {
            vf2 o = {a0 + b2.x, a1 + b2.y};
            __builtin_nontemporal_store(o, (vf2*)(out + (size_t)node * D_FEAT) + col);
        }
    }

    // Safety tails (statistically never executed). Same-block rows only; the
    // barrier orders them after the epilogue stores.
    __syncthreads();
    if (lmask) {
#pragma unroll
        for (int k = 0; k < GB_EPT; ++k) {
            if ((lmask >> k) & 1) {
                int r = ((unsigned)xk[k] >> 24) - rlo;
                int s = xk[k] & 0xFFFFFF;
                int node = bk * BUCK_NODES + rlo + r;
                for (int d = 0; d < D_FEAT; ++d)
                    atomicAdd(&out[(size_t)node * D_FEAT + d], wk[k] * feat[s * D_FEAT + d]);
            }
        }
    }
    for (int idx = nEc + t; idx < nE; idx += GB_BLK) {
        int2 e = ep[g0 + idx];
        int r = ((unsigned)e.x >> 24) - rlo;
        if ((unsigned)r < HALF_NODES) {
            int s = e.x & 0xFFFFFF;
            float w = __int_as_float(e.y);
            int node = bk * BUCK_NODES + rlo + r;
            for (int d = 0; d < D_FEAT; ++d)
                atomicAdd(&out[(size_t)node * D_FEAT + d], w * feat[s * D_FEAT + d]);
        }
    }
}

// ---------------- fallback (ws too small): direct atomic path ---------------
__global__ void init_out_kernel(const float* __restrict__ bias,
                                float* __restrict__ out) {
    int i = blockIdx.x * blockDim.x + threadIdx.x;
    if (i < N_NODES * D_FEAT) out[i] = bias[i & (D_FEAT - 1)];
}

__global__ void edge_scatter_kernel(const float* __restrict__ feat,
                                    const float* __restrict__ weight,
                                    const int* __restrict__ src,
                                    const int* __restrict__ dst,
                                    float* __restrict__ out) {
    int e = blockIdx.x * 4 + (threadIdx.x >> 6);
    int lane = threadIdx.x & 63;
    if (e < N_EDGES) {
        atomicAdd(&out[dst[e] * D_FEAT + lane], weight[e] * feat[src[e] * D_FEAT + lane]);
    }
}

extern "C" void kernel_launch(void* const* d_in, const int* in_sizes, int n_in,
                              void* d_out, int out_size, void* d_ws, size_t ws_size,
                              hipStream_t stream) {
    const float* feat   = (const float*)d_in[0];
    const float* weight = (const float*)d_in[1];
    const float* bias   = (const float*)d_in[2];
    const int*   src    = (const int*)d_in[3];
    const int*   dst    = (const int*)d_in[4];
    float* out = (float*)d_out;

    if (ws_size < WS_MED) {
        int total = N_NODES * D_FEAT;
        init_out_kernel<<<(total + 255) / 256, 256, 0, stream>>>(bias, out);
        edge_scatter_kernel<<<(N_EDGES + 3) / 4, 256, 0, stream>>>(feat, weight, src, dst, out);
        return;
    }

    char* ws = (char*)d_ws;
    int*      bcnt  = (int*)(ws + OFF_BCNT);
    int*      bbase = (int*)(ws + OFF_BBASE);
    int*      bcur  = (int*)(ws + OFF_BCUR);
    int2*     ep    = (int2*)(ws + OFF_EP);
    ushort_t* featb = (ushort_t*)(ws + OFF_FEATB);
    const bool use_bf16 = (ws_size >= WS_FULL);

    (void)hipMemsetAsync(bcnt, 0, NBUCK * sizeof(int), stream);
    if (use_bf16)
        k_prep<<<(NFEAT_ELEM / 4 + 255) / 256, 256, 0, stream>>>(feat, featb);
    k_bhist<<<256, 256, 0, stream>>>(dst, bcnt);
    k_bscan<<<1, 1024, 0, stream>>>(bcnt, bbase, bcur);
    k_bin<<<NCHUNK, BIN_BLK, 0, stream>>>(src, dst, weight, bcur, ep);
    if (use_bf16)
        k_sgather<1><<<NBUCK * 2, GB_BLK, 0, stream>>>(feat, featb, bias, bbase, ep, out);
    else
        k_sgather<0><<<NBUCK * 2, GB_BLK, 0, stream>>>(feat, featb, bias, bbase, ep, out);
}